// Round 1
// baseline (409.147 us; speedup 1.0000x reference)
//
#include <hip/hip_runtime.h>
#include <math.h>

#define N_RES 768
#define DISTO_BINS 64
#define LDDT_BINS 50
#define DISTO_GRID 2048

// ---------------- Kernel A: distogram CE partial sums ----------------
// One 64-lane wave per (i,j) pair; lane l holds logits[p*64+l].
__global__ void disto_partial_kernel(const float* __restrict__ logits,
                                     const float* __restrict__ pb,
                                     const float* __restrict__ pbm,
                                     float* __restrict__ partial) {
    const int lane = threadIdx.x & 63;
    const int wid  = threadIdx.x >> 6;
    const int wpb  = blockDim.x >> 6;
    const int gw   = blockIdx.x * wpb + wid;
    const int nw   = gridDim.x * wpb;
    const int npairs = N_RES * N_RES;

    float acc = 0.f;
    for (int p = gw; p < npairs; p += nw) {
        const int i = p / N_RES;
        const int j = p - i * N_RES;

        float x = logits[p * DISTO_BINS + lane];
        float s = __expf(x);
#pragma unroll
        for (int off = 32; off > 0; off >>= 1) s += __shfl_xor(s, off, 64);

        // true bin: count of boundaries (2.3125+0.3125k)^2 < d2, k=0..62
        float dx = pb[3 * i + 0] - pb[3 * j + 0];
        float dy = pb[3 * i + 1] - pb[3 * j + 1];
        float dz = pb[3 * i + 2] - pb[3 * j + 2];
        float d2 = dx * dx + dy * dy + dz * dz;
        float d  = sqrtf(d2);
        float t  = ceilf((d - 2.3125f) * 3.2f);   // 1/0.3125 = 3.2 exact
        int bin  = (int)fminf(fmaxf(t, 0.f), 63.f);

        float xb  = __shfl(x, bin, 64);
        float err = __logf(s) - xb;               // -log_softmax[bin]
        if (lane == 0) acc += err * pbm[i] * pbm[j];
    }

    __shared__ float wsum[16];
    if (lane == 0) wsum[wid] = acc;
    __syncthreads();
    if (threadIdx.x == 0) {
        float b = 0.f;
        for (int w = 0; w < wpb; ++w) b += wsum[w];
        partial[blockIdx.x] = b;
    }
}

// ---------------- Kernel B: per-residue lddt + CE ----------------
__global__ void lddt_kernel(const float* __restrict__ pred37,   // (N,37,3)
                            const float* __restrict__ true37,   // (N,37,3)
                            const float* __restrict__ mask37,   // (N,37)
                            const float* __restrict__ lddt_logits, // (N,50)
                            float* __restrict__ errm) {
    const int i   = blockIdx.x;
    const int tid = threadIdx.x;
    const int nthr = blockDim.x;

    const float tix = true37[(i * 37 + 1) * 3 + 0];
    const float tiy = true37[(i * 37 + 1) * 3 + 1];
    const float tiz = true37[(i * 37 + 1) * 3 + 2];
    const float pix = pred37[(i * 37 + 1) * 3 + 0];
    const float piy = pred37[(i * 37 + 1) * 3 + 1];
    const float piz = pred37[(i * 37 + 1) * 3 + 2];
    const float mi  = mask37[i * 37 + 1];

    float scope_sum = 0.f, score_sum = 0.f;
    for (int j = tid; j < N_RES; j += nthr) {
        float mj  = mask37[j * 37 + 1];
        float dtx = tix - true37[(j * 37 + 1) * 3 + 0];
        float dty = tiy - true37[(j * 37 + 1) * 3 + 1];
        float dtz = tiz - true37[(j * 37 + 1) * 3 + 2];
        float dt  = sqrtf(1e-10f + dtx * dtx + dty * dty + dtz * dtz);
        float dpx = pix - pred37[(j * 37 + 1) * 3 + 0];
        float dpy = piy - pred37[(j * 37 + 1) * 3 + 1];
        float dpz = piz - pred37[(j * 37 + 1) * 3 + 2];
        float dp  = sqrtf(1e-10f + dpx * dpx + dpy * dpy + dpz * dpz);
        float scope = (dt < 15.f && j != i) ? (mi * mj) : 0.f;
        float l1 = fabsf(dt - dp);
        float sc = 0.25f * ((l1 < 0.5f ? 1.f : 0.f) + (l1 < 1.f ? 1.f : 0.f) +
                            (l1 < 2.f ? 1.f : 0.f) + (l1 < 4.f ? 1.f : 0.f));
        scope_sum += scope;
        score_sum += scope * sc;
    }

    __shared__ float r1[128], r2[128];
    r1[tid] = scope_sum;
    r2[tid] = score_sum;
    __syncthreads();
    for (int s = nthr >> 1; s > 0; s >>= 1) {
        if (tid < s) { r1[tid] += r1[tid + s]; r2[tid] += r2[tid + s]; }
        __syncthreads();
    }

    __shared__ int binS;
    if (tid == 0) {
        float lddt = (1e-10f + r2[0]) / (1e-10f + r1[0]);
        int bin = (int)floorf(lddt * (float)LDDT_BINS);
        binS = min(max(bin, 0), LDDT_BINS - 1);
    }
    __syncthreads();

    // CE over 50 bins (no max-sub; logits ~N(0,1))
    float e = (tid < LDDT_BINS) ? __expf(lddt_logits[i * LDDT_BINS + tid]) : 0.f;
    r1[tid] = e;
    __syncthreads();
    for (int s = nthr >> 1; s > 0; s >>= 1) {
        if (tid < s) r1[tid] += r1[tid + s];
        __syncthreads();
    }
    if (tid == 0) {
        float err = __logf(r1[0]) - lddt_logits[i * LDDT_BINS + binS];
        errm[i] = err * mi;
    }
}

// ---------------- Kernel C: final combine ----------------
__global__ void finalize_kernel(const float* __restrict__ partial, int nparts,
                                const float* __restrict__ pbm,     // (N,)
                                const float* __restrict__ errm,    // (N,)
                                const float* __restrict__ mask37,  // (N,37)
                                const float* __restrict__ exl,     // (N,37)
                                const float* __restrict__ a37ex,   // (N,37)
                                const float* __restrict__ resolution,
                                float* __restrict__ out) {
    const int tid = threadIdx.x;
    const int nthr = blockDim.x;

    double sd = 0.0, sm = 0.0, se = 0.0, smca = 0.0, num = 0.0, den = 0.0;
    for (int k = tid; k < nparts; k += nthr) sd += (double)partial[k];
    for (int k = tid; k < N_RES; k += nthr) {
        sm   += (double)pbm[k];
        se   += (double)errm[k];
        smca += (double)mask37[k * 37 + 1];
    }
    for (int k = tid; k < N_RES * 37; k += nthr) {
        float x  = exl[k];
        float m  = mask37[k];
        float ex = a37ex[k];
        // log_sigmoid(x), numerically stable
        float ls  = (x >= 0.f) ? -log1pf(__expf(-x)) : (x - log1pf(__expf(x)));
        float lsn = ls - x;  // log_sigmoid(-x)
        float err = -(m * ls + (1.f - m) * lsn);
        num += (double)(err * ex);
        den += (double)ex;
    }

    __shared__ double red[256];
    double vals[6] = {sd, sm, se, smca, num, den};
    double tot[6];
    for (int v = 0; v < 6; ++v) {
        red[tid] = vals[v];
        __syncthreads();
        for (int s = nthr >> 1; s > 0; s >>= 1) {
            if (tid < s) red[tid] += red[tid + s];
            __syncthreads();
        }
        tot[v] = red[0];
        __syncthreads();
    }

    if (tid == 0) {
        float res = resolution[0];
        double gate = (res >= 0.1f && res <= 3.0f) ? 1.0 : 0.0;
        double l_disto = tot[0] / (1e-6 + tot[1] * tot[1]);
        double l_plddt = tot[2] / (1e-10 + tot[3]) * gate;
        double l_exp   = tot[4] / (1e-8 + tot[5]) * gate;
        out[0] = (float)(0.3 * l_disto + 0.01 * l_plddt + 0.01 * l_exp);
    }
}

extern "C" void kernel_launch(void* const* d_in, const int* in_sizes, int n_in,
                              void* d_out, int out_size, void* d_ws, size_t ws_size,
                              hipStream_t stream) {
    const float* disto       = (const float*)d_in[0];  // (1,768,768,64)
    const float* pb          = (const float*)d_in[1];  // (1,768,3)
    const float* pbm         = (const float*)d_in[2];  // (1,768)
    const float* lddt_logits = (const float*)d_in[3];  // (1,768,50)
    const float* pred        = (const float*)d_in[4];  // (1,768,37,3)
    const float* truep       = (const float*)d_in[5];  // (1,768,37,3)
    const float* am          = (const float*)d_in[6];  // (1,768,37)
    const float* exl         = (const float*)d_in[7];  // (1,768,37)
    const float* a37         = (const float*)d_in[8];  // (1,768,37)
    const float* resolution  = (const float*)d_in[9];  // (1,)
    float* out = (float*)d_out;

    float* ws      = (float*)d_ws;
    float* partial = ws;               // DISTO_GRID floats
    float* errm    = ws + DISTO_GRID;  // N_RES floats

    disto_partial_kernel<<<DISTO_GRID, 256, 0, stream>>>(disto, pb, pbm, partial);
    lddt_kernel<<<N_RES, 128, 0, stream>>>(pred, truep, am, lddt_logits, errm);
    finalize_kernel<<<1, 256, 0, stream>>>(partial, DISTO_GRID, pbm, errm, am,
                                           exl, a37, resolution, out);
}

// Round 2
// 347.705 us; speedup vs baseline: 1.1767x; 1.1767x over previous
//
#include <hip/hip_runtime.h>
#include <math.h>

#define N_RES 768
#define DISTO_BINS 64
#define LDDT_BINS 50
#define DISTO_GRID 2048

// ---------------- Kernel A: distogram CE partial sums ----------------
// One wave processes 4 pairs per chunk: lane l loads float4 = logits
// elements [4l,4l+4) of a 256-element chunk; lanes 16q..16q+15 hold pair q.
__global__ __launch_bounds__(256)
void disto_partial_kernel(const float4* __restrict__ logits4,
                          const float* __restrict__ pb,
                          const float* __restrict__ pbm,
                          float* __restrict__ partial) {
    __shared__ float spb[N_RES * 3];
    __shared__ float spm[N_RES];
    for (int k = threadIdx.x; k < N_RES * 3; k += blockDim.x) spb[k] = pb[k];
    for (int k = threadIdx.x; k < N_RES; k += blockDim.x) spm[k] = pbm[k];
    __syncthreads();

    const int lane = threadIdx.x & 63;
    const int wid  = threadIdx.x >> 6;
    const int q    = lane >> 4;    // pair-group 0..3 within wave
    const int gl   = lane & 15;    // lane within group
    const int gw   = blockIdx.x * 4 + wid;
    const int nw   = DISTO_GRID * 4;
    const int nchunks = (N_RES * N_RES) / 4;   // 147456

    float acc = 0.f;
    for (int c = gw; c < nchunks; c += 2 * nw) {
        const int c2 = c + nw;
        // issue both loads up front (2 outstanding vmem ops)
        float4 xa = logits4[(size_t)c * 64 + lane];
        float4 xb = (c2 < nchunks) ? logits4[(size_t)c2 * 64 + lane]
                                   : make_float4(0.f, 0.f, 0.f, 0.f);

        // ---- chunk c ----
        {
            float e = __expf(xa.x) + __expf(xa.y) + __expf(xa.z) + __expf(xa.w);
            e += __shfl_xor(e, 1, 64);
            e += __shfl_xor(e, 2, 64);
            e += __shfl_xor(e, 4, 64);
            e += __shfl_xor(e, 8, 64);
            int p = c * 4 + q;
            int i = p / N_RES;
            int j = p - i * N_RES;
            float dx = spb[3 * i + 0] - spb[3 * j + 0];
            float dy = spb[3 * i + 1] - spb[3 * j + 1];
            float dz = spb[3 * i + 2] - spb[3 * j + 2];
            float d  = sqrtf(dx * dx + dy * dy + dz * dz);
            float t  = ceilf((d - 2.3125f) * 3.2f);
            int bin  = (int)fminf(fmaxf(t, 0.f), 63.f);
            float xs = (bin & 2) ? ((bin & 1) ? xa.w : xa.z)
                                 : ((bin & 1) ? xa.y : xa.x);
            float xv = __shfl(xs, (q << 4) + (bin >> 2), 64);
            if (gl == 0) acc += (__logf(e) - xv) * spm[i] * spm[j];
        }
        // ---- chunk c2 ----
        if (c2 < nchunks) {
            float e = __expf(xb.x) + __expf(xb.y) + __expf(xb.z) + __expf(xb.w);
            e += __shfl_xor(e, 1, 64);
            e += __shfl_xor(e, 2, 64);
            e += __shfl_xor(e, 4, 64);
            e += __shfl_xor(e, 8, 64);
            int p = c2 * 4 + q;
            int i = p / N_RES;
            int j = p - i * N_RES;
            float dx = spb[3 * i + 0] - spb[3 * j + 0];
            float dy = spb[3 * i + 1] - spb[3 * j + 1];
            float dz = spb[3 * i + 2] - spb[3 * j + 2];
            float d  = sqrtf(dx * dx + dy * dy + dz * dz);
            float t  = ceilf((d - 2.3125f) * 3.2f);
            int bin  = (int)fminf(fmaxf(t, 0.f), 63.f);
            float xs = (bin & 2) ? ((bin & 1) ? xb.w : xb.z)
                                 : ((bin & 1) ? xb.y : xb.x);
            float xv = __shfl(xs, (q << 4) + (bin >> 2), 64);
            if (gl == 0) acc += (__logf(e) - xv) * spm[i] * spm[j];
        }
    }

    // acc lives on lanes 0,16,32,48 of each wave
    acc += __shfl_xor(acc, 16, 64);
    acc += __shfl_xor(acc, 32, 64);
    __shared__ float wsum[4];
    if (lane == 0) wsum[wid] = acc;
    __syncthreads();
    if (threadIdx.x == 0)
        partial[blockIdx.x] = wsum[0] + wsum[1] + wsum[2] + wsum[3];
}

// ---------------- Kernel B: per-residue lddt + CE ----------------
__global__ void lddt_kernel(const float* __restrict__ pred37,   // (N,37,3)
                            const float* __restrict__ true37,   // (N,37,3)
                            const float* __restrict__ mask37,   // (N,37)
                            const float* __restrict__ lddt_logits, // (N,50)
                            float* __restrict__ errm) {
    const int i   = blockIdx.x;
    const int tid = threadIdx.x;
    const int nthr = blockDim.x;

    const float tix = true37[(i * 37 + 1) * 3 + 0];
    const float tiy = true37[(i * 37 + 1) * 3 + 1];
    const float tiz = true37[(i * 37 + 1) * 3 + 2];
    const float pix = pred37[(i * 37 + 1) * 3 + 0];
    const float piy = pred37[(i * 37 + 1) * 3 + 1];
    const float piz = pred37[(i * 37 + 1) * 3 + 2];
    const float mi  = mask37[i * 37 + 1];

    float scope_sum = 0.f, score_sum = 0.f;
    for (int j = tid; j < N_RES; j += nthr) {
        float mj  = mask37[j * 37 + 1];
        float dtx = tix - true37[(j * 37 + 1) * 3 + 0];
        float dty = tiy - true37[(j * 37 + 1) * 3 + 1];
        float dtz = tiz - true37[(j * 37 + 1) * 3 + 2];
        float dt  = sqrtf(1e-10f + dtx * dtx + dty * dty + dtz * dtz);
        float dpx = pix - pred37[(j * 37 + 1) * 3 + 0];
        float dpy = piy - pred37[(j * 37 + 1) * 3 + 1];
        float dpz = piz - pred37[(j * 37 + 1) * 3 + 2];
        float dp  = sqrtf(1e-10f + dpx * dpx + dpy * dpy + dpz * dpz);
        float scope = (dt < 15.f && j != i) ? (mi * mj) : 0.f;
        float l1 = fabsf(dt - dp);
        float sc = 0.25f * ((l1 < 0.5f ? 1.f : 0.f) + (l1 < 1.f ? 1.f : 0.f) +
                            (l1 < 2.f ? 1.f : 0.f) + (l1 < 4.f ? 1.f : 0.f));
        scope_sum += scope;
        score_sum += scope * sc;
    }

    __shared__ float r1[128], r2[128];
    r1[tid] = scope_sum;
    r2[tid] = score_sum;
    __syncthreads();
    for (int s = nthr >> 1; s > 0; s >>= 1) {
        if (tid < s) { r1[tid] += r1[tid + s]; r2[tid] += r2[tid + s]; }
        __syncthreads();
    }

    __shared__ int binS;
    if (tid == 0) {
        float lddt = (1e-10f + r2[0]) / (1e-10f + r1[0]);
        int bin = (int)floorf(lddt * (float)LDDT_BINS);
        binS = min(max(bin, 0), LDDT_BINS - 1);
    }
    __syncthreads();

    float e = (tid < LDDT_BINS) ? __expf(lddt_logits[i * LDDT_BINS + tid]) : 0.f;
    r1[tid] = e;
    __syncthreads();
    for (int s = nthr >> 1; s > 0; s >>= 1) {
        if (tid < s) r1[tid] += r1[tid + s];
        __syncthreads();
    }
    if (tid == 0) {
        float err = __logf(r1[0]) - lddt_logits[i * LDDT_BINS + binS];
        errm[i] = err * mi;
    }
}

// ---------------- Kernel C: final combine ----------------
__global__ void finalize_kernel(const float* __restrict__ partial, int nparts,
                                const float* __restrict__ pbm,     // (N,)
                                const float* __restrict__ errm,    // (N,)
                                const float* __restrict__ mask37,  // (N,37)
                                const float* __restrict__ exl,     // (N,37)
                                const float* __restrict__ a37ex,   // (N,37)
                                const float* __restrict__ resolution,
                                float* __restrict__ out) {
    const int tid = threadIdx.x;
    const int nthr = blockDim.x;

    double sd = 0.0, sm = 0.0, se = 0.0, smca = 0.0, num = 0.0, den = 0.0;
    for (int k = tid; k < nparts; k += nthr) sd += (double)partial[k];
    for (int k = tid; k < N_RES; k += nthr) {
        sm   += (double)pbm[k];
        se   += (double)errm[k];
        smca += (double)mask37[k * 37 + 1];
    }
    for (int k = tid; k < N_RES * 37; k += nthr) {
        float x  = exl[k];
        float m  = mask37[k];
        float ex = a37ex[k];
        float ls  = (x >= 0.f) ? -log1pf(__expf(-x)) : (x - log1pf(__expf(x)));
        float lsn = ls - x;  // log_sigmoid(-x)
        float err = -(m * ls + (1.f - m) * lsn);
        num += (double)(err * ex);
        den += (double)ex;
    }

    __shared__ double red[256];
    double vals[6] = {sd, sm, se, smca, num, den};
    double tot[6];
    for (int v = 0; v < 6; ++v) {
        red[tid] = vals[v];
        __syncthreads();
        for (int s = nthr >> 1; s > 0; s >>= 1) {
            if (tid < s) red[tid] += red[tid + s];
            __syncthreads();
        }
        tot[v] = red[0];
        __syncthreads();
    }

    if (tid == 0) {
        float res = resolution[0];
        double gate = (res >= 0.1f && res <= 3.0f) ? 1.0 : 0.0;
        double l_disto = tot[0] / (1e-6 + tot[1] * tot[1]);
        double l_plddt = tot[2] / (1e-10 + tot[3]) * gate;
        double l_exp   = tot[4] / (1e-8 + tot[5]) * gate;
        out[0] = (float)(0.3 * l_disto + 0.01 * l_plddt + 0.01 * l_exp);
    }
}

extern "C" void kernel_launch(void* const* d_in, const int* in_sizes, int n_in,
                              void* d_out, int out_size, void* d_ws, size_t ws_size,
                              hipStream_t stream) {
    const float* disto       = (const float*)d_in[0];  // (1,768,768,64)
    const float* pb          = (const float*)d_in[1];  // (1,768,3)
    const float* pbm         = (const float*)d_in[2];  // (1,768)
    const float* lddt_logits = (const float*)d_in[3];  // (1,768,50)
    const float* pred        = (const float*)d_in[4];  // (1,768,37,3)
    const float* truep       = (const float*)d_in[5];  // (1,768,37,3)
    const float* am          = (const float*)d_in[6];  // (1,768,37)
    const float* exl         = (const float*)d_in[7];  // (1,768,37)
    const float* a37         = (const float*)d_in[8];  // (1,768,37)
    const float* resolution  = (const float*)d_in[9];  // (1,)
    float* out = (float*)d_out;

    float* ws      = (float*)d_ws;
    float* partial = ws;               // DISTO_GRID floats
    float* errm    = ws + DISTO_GRID;  // N_RES floats

    disto_partial_kernel<<<DISTO_GRID, 256, 0, stream>>>(
        (const float4*)disto, pb, pbm, partial);
    lddt_kernel<<<N_RES, 128, 0, stream>>>(pred, truep, am, lddt_logits, errm);
    finalize_kernel<<<1, 256, 0, stream>>>(partial, DISTO_GRID, pbm, errm, am,
                                           exl, a37, resolution, out);
}

// Round 3
// 251.236 us; speedup vs baseline: 1.6285x; 1.3840x over previous
//
#include <hip/hip_runtime.h>
#include <math.h>

#define N_RES 768
#define DISTO_BINS 64
#define LDDT_BINS 50
#define DISTO_GRID 2048
#define EXP_GRID 64

// ---------------- Kernel A: distogram CE partial sums ----------------
// One wave processes 4 pairs per chunk: lane l loads float4 = logits
// elements [4l,4l+4) of a 256-element chunk; lanes 16q..16q+15 hold pair q.
__global__ __launch_bounds__(256)
void disto_partial_kernel(const float4* __restrict__ logits4,
                          const float* __restrict__ pb,
                          const float* __restrict__ pbm,
                          float* __restrict__ partial) {
    __shared__ float spb[N_RES * 3];
    __shared__ float spm[N_RES];
    for (int k = threadIdx.x; k < N_RES * 3; k += blockDim.x) spb[k] = pb[k];
    for (int k = threadIdx.x; k < N_RES; k += blockDim.x) spm[k] = pbm[k];
    __syncthreads();

    const int lane = threadIdx.x & 63;
    const int wid  = threadIdx.x >> 6;
    const int q    = lane >> 4;    // pair-group 0..3 within wave
    const int gl   = lane & 15;    // lane within group
    const int gw   = blockIdx.x * 4 + wid;
    const int nw   = DISTO_GRID * 4;
    const int nchunks = (N_RES * N_RES) / 4;   // 147456

    float acc = 0.f;
    for (int c = gw; c < nchunks; c += 2 * nw) {
        const int c2 = c + nw;
        float4 xa = logits4[(size_t)c * 64 + lane];
        float4 xb = (c2 < nchunks) ? logits4[(size_t)c2 * 64 + lane]
                                   : make_float4(0.f, 0.f, 0.f, 0.f);

        {
            float e = __expf(xa.x) + __expf(xa.y) + __expf(xa.z) + __expf(xa.w);
            e += __shfl_xor(e, 1, 64);
            e += __shfl_xor(e, 2, 64);
            e += __shfl_xor(e, 4, 64);
            e += __shfl_xor(e, 8, 64);
            int p = c * 4 + q;
            int i = p / N_RES;
            int j = p - i * N_RES;
            float dx = spb[3 * i + 0] - spb[3 * j + 0];
            float dy = spb[3 * i + 1] - spb[3 * j + 1];
            float dz = spb[3 * i + 2] - spb[3 * j + 2];
            float d  = sqrtf(dx * dx + dy * dy + dz * dz);
            float t  = ceilf((d - 2.3125f) * 3.2f);
            int bin  = (int)fminf(fmaxf(t, 0.f), 63.f);
            float xs = (bin & 2) ? ((bin & 1) ? xa.w : xa.z)
                                 : ((bin & 1) ? xa.y : xa.x);
            float xv = __shfl(xs, (q << 4) + (bin >> 2), 64);
            if (gl == 0) acc += (__logf(e) - xv) * spm[i] * spm[j];
        }
        if (c2 < nchunks) {
            float e = __expf(xb.x) + __expf(xb.y) + __expf(xb.z) + __expf(xb.w);
            e += __shfl_xor(e, 1, 64);
            e += __shfl_xor(e, 2, 64);
            e += __shfl_xor(e, 4, 64);
            e += __shfl_xor(e, 8, 64);
            int p = c2 * 4 + q;
            int i = p / N_RES;
            int j = p - i * N_RES;
            float dx = spb[3 * i + 0] - spb[3 * j + 0];
            float dy = spb[3 * i + 1] - spb[3 * j + 1];
            float dz = spb[3 * i + 2] - spb[3 * j + 2];
            float d  = sqrtf(dx * dx + dy * dy + dz * dz);
            float t  = ceilf((d - 2.3125f) * 3.2f);
            int bin  = (int)fminf(fmaxf(t, 0.f), 63.f);
            float xs = (bin & 2) ? ((bin & 1) ? xb.w : xb.z)
                                 : ((bin & 1) ? xb.y : xb.x);
            float xv = __shfl(xs, (q << 4) + (bin >> 2), 64);
            if (gl == 0) acc += (__logf(e) - xv) * spm[i] * spm[j];
        }
    }

    acc += __shfl_xor(acc, 16, 64);
    acc += __shfl_xor(acc, 32, 64);
    __shared__ float wsum[4];
    if (lane == 0) wsum[wid] = acc;
    __syncthreads();
    if (threadIdx.x == 0)
        partial[blockIdx.x] = wsum[0] + wsum[1] + wsum[2] + wsum[3];
}

// ---------------- Kernel B: per-residue lddt + CE ----------------
__global__ void lddt_kernel(const float* __restrict__ pred37,   // (N,37,3)
                            const float* __restrict__ true37,   // (N,37,3)
                            const float* __restrict__ mask37,   // (N,37)
                            const float* __restrict__ lddt_logits, // (N,50)
                            float* __restrict__ errm) {
    const int i   = blockIdx.x;
    const int tid = threadIdx.x;
    const int nthr = blockDim.x;

    const float tix = true37[(i * 37 + 1) * 3 + 0];
    const float tiy = true37[(i * 37 + 1) * 3 + 1];
    const float tiz = true37[(i * 37 + 1) * 3 + 2];
    const float pix = pred37[(i * 37 + 1) * 3 + 0];
    const float piy = pred37[(i * 37 + 1) * 3 + 1];
    const float piz = pred37[(i * 37 + 1) * 3 + 2];
    const float mi  = mask37[i * 37 + 1];

    float scope_sum = 0.f, score_sum = 0.f;
    for (int j = tid; j < N_RES; j += nthr) {
        float mj  = mask37[j * 37 + 1];
        float dtx = tix - true37[(j * 37 + 1) * 3 + 0];
        float dty = tiy - true37[(j * 37 + 1) * 3 + 1];
        float dtz = tiz - true37[(j * 37 + 1) * 3 + 2];
        float dt  = sqrtf(1e-10f + dtx * dtx + dty * dty + dtz * dtz);
        float dpx = pix - pred37[(j * 37 + 1) * 3 + 0];
        float dpy = piy - pred37[(j * 37 + 1) * 3 + 1];
        float dpz = piz - pred37[(j * 37 + 1) * 3 + 2];
        float dp  = sqrtf(1e-10f + dpx * dpx + dpy * dpy + dpz * dpz);
        float scope = (dt < 15.f && j != i) ? (mi * mj) : 0.f;
        float l1 = fabsf(dt - dp);
        float sc = 0.25f * ((l1 < 0.5f ? 1.f : 0.f) + (l1 < 1.f ? 1.f : 0.f) +
                            (l1 < 2.f ? 1.f : 0.f) + (l1 < 4.f ? 1.f : 0.f));
        scope_sum += scope;
        score_sum += scope * sc;
    }

    __shared__ float r1[128], r2[128];
    r1[tid] = scope_sum;
    r2[tid] = score_sum;
    __syncthreads();
    for (int s = nthr >> 1; s > 0; s >>= 1) {
        if (tid < s) { r1[tid] += r1[tid + s]; r2[tid] += r2[tid + s]; }
        __syncthreads();
    }

    __shared__ int binS;
    if (tid == 0) {
        float lddt = (1e-10f + r2[0]) / (1e-10f + r1[0]);
        int bin = (int)floorf(lddt * (float)LDDT_BINS);
        binS = min(max(bin, 0), LDDT_BINS - 1);
    }
    __syncthreads();

    float e = (tid < LDDT_BINS) ? __expf(lddt_logits[i * LDDT_BINS + tid]) : 0.f;
    r1[tid] = e;
    __syncthreads();
    for (int s = nthr >> 1; s > 0; s >>= 1) {
        if (tid < s) r1[tid] += r1[tid + s];
        __syncthreads();
    }
    if (tid == 0) {
        float err = __logf(r1[0]) - lddt_logits[i * LDDT_BINS + binS];
        errm[i] = err * mi;
    }
}

// ---------------- Kernel B2: exp-resolved partial sums ----------------
__global__ __launch_bounds__(256)
void exp_partial_kernel(const float* __restrict__ exl,     // (N,37)
                        const float* __restrict__ mask37,  // (N,37)
                        const float* __restrict__ a37ex,   // (N,37)
                        float* __restrict__ expnum,        // (EXP_GRID)
                        float* __restrict__ expden) {      // (EXP_GRID)
    const int tid = threadIdx.x;
    const int gid = blockIdx.x * blockDim.x + tid;
    const int stride = gridDim.x * blockDim.x;
    const int n = N_RES * 37;

    float num = 0.f, den = 0.f;
    for (int k = gid; k < n; k += stride) {
        float x  = exl[k];
        float m  = mask37[k];
        float ex = a37ex[k];
        // softplus(-x) = -log_sigmoid(x), stable
        float ax = fabsf(x);
        float sp = __logf(1.f + __expf(-ax));     // softplus(-|x|)
        float ls  = sp + fmaxf(-x, 0.f);          // softplus(-x)
        float lsn = sp + fmaxf(x, 0.f);           // softplus(x)
        float err = m * ls + (1.f - m) * lsn;
        num += err * ex;
        den += ex;
    }

    __shared__ float r1[256], r2[256];
    r1[tid] = num;
    r2[tid] = den;
    __syncthreads();
    for (int s = 128; s > 0; s >>= 1) {
        if (tid < s) { r1[tid] += r1[tid + s]; r2[tid] += r2[tid + s]; }
        __syncthreads();
    }
    if (tid == 0) { expnum[blockIdx.x] = r1[0]; expden[blockIdx.x] = r2[0]; }
}

// ---------------- Kernel C: final combine (small reductions only) --------
__global__ __launch_bounds__(256)
void finalize_kernel(const float* __restrict__ partial,  // (DISTO_GRID)
                     const float* __restrict__ pbm,      // (N,)
                     const float* __restrict__ errm,     // (N,)
                     const float* __restrict__ mask37,   // (N,37)
                     const float* __restrict__ expnum,   // (EXP_GRID)
                     const float* __restrict__ expden,   // (EXP_GRID)
                     const float* __restrict__ resolution,
                     float* __restrict__ out) {
    const int tid = threadIdx.x;
    const int nthr = blockDim.x;

    double sd = 0.0, sm = 0.0, se = 0.0, smca = 0.0, num = 0.0, den = 0.0;
    for (int k = tid; k < DISTO_GRID; k += nthr) sd += (double)partial[k];
    for (int k = tid; k < N_RES; k += nthr) {
        sm   += (double)pbm[k];
        se   += (double)errm[k];
        smca += (double)mask37[k * 37 + 1];
    }
    if (tid < EXP_GRID) { num = (double)expnum[tid]; den = (double)expden[tid]; }

    __shared__ double red[256];
    double vals[6] = {sd, sm, se, smca, num, den};
    double tot[6];
    for (int v = 0; v < 6; ++v) {
        red[tid] = vals[v];
        __syncthreads();
        for (int s = nthr >> 1; s > 0; s >>= 1) {
            if (tid < s) red[tid] += red[tid + s];
            __syncthreads();
        }
        tot[v] = red[0];
        __syncthreads();
    }

    if (tid == 0) {
        float res = resolution[0];
        double gate = (res >= 0.1f && res <= 3.0f) ? 1.0 : 0.0;
        double l_disto = tot[0] / (1e-6 + tot[1] * tot[1]);
        double l_plddt = tot[2] / (1e-10 + tot[3]) * gate;
        double l_exp   = tot[4] / (1e-8 + tot[5]) * gate;
        out[0] = (float)(0.3 * l_disto + 0.01 * l_plddt + 0.01 * l_exp);
    }
}

extern "C" void kernel_launch(void* const* d_in, const int* in_sizes, int n_in,
                              void* d_out, int out_size, void* d_ws, size_t ws_size,
                              hipStream_t stream) {
    const float* disto       = (const float*)d_in[0];  // (1,768,768,64)
    const float* pb          = (const float*)d_in[1];  // (1,768,3)
    const float* pbm         = (const float*)d_in[2];  // (1,768)
    const float* lddt_logits = (const float*)d_in[3];  // (1,768,50)
    const float* pred        = (const float*)d_in[4];  // (1,768,37,3)
    const float* truep       = (const float*)d_in[5];  // (1,768,37,3)
    const float* am          = (const float*)d_in[6];  // (1,768,37)
    const float* exl         = (const float*)d_in[7];  // (1,768,37)
    const float* a37         = (const float*)d_in[8];  // (1,768,37)
    const float* resolution  = (const float*)d_in[9];  // (1,)
    float* out = (float*)d_out;

    float* ws      = (float*)d_ws;
    float* partial = ws;                         // DISTO_GRID
    float* errm    = ws + DISTO_GRID;            // N_RES
    float* expnum  = errm + N_RES;               // EXP_GRID
    float* expden  = expnum + EXP_GRID;          // EXP_GRID

    disto_partial_kernel<<<DISTO_GRID, 256, 0, stream>>>(
        (const float4*)disto, pb, pbm, partial);
    lddt_kernel<<<N_RES, 128, 0, stream>>>(pred, truep, am, lddt_logits, errm);
    exp_partial_kernel<<<EXP_GRID, 256, 0, stream>>>(exl, am, a37, expnum, expden);
    finalize_kernel<<<1, 256, 0, stream>>>(partial, pbm, errm, am,
                                           expnum, expden, resolution, out);
}